// Round 11
// baseline (333.555 us; speedup 1.0000x reference)
//
#include <hip/hip_runtime.h>
#include <math.h>

// Boruvka MST persistent-homology kernel, fused-round variant.
// Correctness: outputs depend only on the MST edge-weight multiset, identical
// for all MSTs under a strict total edge order. Edge order = lexicographic
// (d2_bits, min(i,j), max(i,j)), a strict refinement of the reference's
// sqrt-domain order (sqrtf monotone). d2 computed in the reference's exact
// f32 op order, clamped; sqrtf applied once at the end => bit-exact.
//
// Fusion scheme: kernel r = [redundant local merge of round r-1 picks] +
// [best-edge scan of round r]. Every block of a batch replays the merge from
// the same global snapshot; union-find roots are schedule-independent, so all
// blocks derive identical labels without cross-block sync. Candidate buffers
// cb[2] are round-parity double-buffered and keys carry tag=ROUNDS-r in bits
// [57:54]: stale entries (old tag / 0xAA poison / ~0 init) never validate and
// always lose atomicMin (real keys have top bits 0). Labels comp[2] are
// parity double-buffered so the single writer block never races readers.

#define PH_N   2048
#define PH_B   16
#define PH_F   50
#define MAXPTS 100
#define ROUNDS 11            // 11 best-rounds guarantee convergence (halving)
#define RB     16            // row-blocks per batch
#define RPB    (PH_N / RB)   // 128 rows per block
#define TPB    256
#define JPL    32            // j's per lane (2048/64)

typedef unsigned long long u64;
typedef unsigned int u32;
typedef unsigned short u16;

__device__ __forceinline__ float sq3(float x, float y, float z) {
    return __fadd_rn(__fadd_rn(__fmul_rn(x, x), __fmul_rn(y, y)), __fmul_rn(z, z));
}
// d2 exactly as reference: (sq_p + sq_q) - 2*dot, no fma contraction
__device__ __forceinline__ float d2f(float px, float py, float pz, float ps,
                                     float qx, float qy, float qz, float qs) {
    float dot = __fadd_rn(__fadd_rn(__fmul_rn(px, qx), __fmul_rn(py, qy)),
                          __fmul_rn(pz, qz));
    return __fsub_rn(__fadd_rn(ps, qs), __fmul_rn(2.0f, dot));
}

template<int CTRL>
__device__ __forceinline__ float dpp_min(float v) {
    int vi = __float_as_int(v);
    int sh = __builtin_amdgcn_update_dpp(vi, vi, CTRL, 0xF, 0xF, false);
    return fminf(v, __int_as_float(sh));
}
template<int CTRL>
__device__ __forceinline__ int dpp_imin(int v) {
    int sh = __builtin_amdgcn_update_dpp(v, v, CTRL, 0xF, 0xF, false);
    return min(v, sh);
}

__global__ void k_init(u64* __restrict__ cb, int* __restrict__ cnt) {
    const size_t n = (size_t)2 * PH_B * PH_N;
    for (size_t i = (size_t)blockIdx.x * blockDim.x + threadIdx.x; i < n;
         i += (size_t)gridDim.x * blockDim.x)
        cb[i] = ~0ULL;
    if (blockIdx.x == 0 && threadIdx.x < PH_B) cnt[threadIdx.x] = 0;
}

// One Boruvka round: merge round r-1 picks (redundant per block), then find
// round r per-component min edges. r==0: no merge. r==ROUNDS: merge only.
__global__ __launch_bounds__(TPB, 1)
void k_round(const float* __restrict__ x, u64* __restrict__ cb,
             int* __restrict__ comp, float* __restrict__ dD2,
             int* __restrict__ cnt, int r)
{
    __shared__ float4 spts[PH_N];   // 32 KB (best phase only)
    __shared__ u16    scomp[PH_N];  // 4 KB
    __shared__ u64    sbest[PH_N];  // 16 KB: merge snapshot, then best mins
    __shared__ u16    sp[PH_N];     // 4 KB union-find parents

    const int rb = blockIdx.x, b = blockIdx.y, tid = threadIdx.x;
    const int lane = tid & 63, wave = tid >> 6;
    const size_t bN = (size_t)b * PH_N;
    const int par = r & 1;
    u64* cbw = cb + (size_t)par * PH_B * PH_N + bN;         // best(r) flush
    u64* cbr = cb + (size_t)(par ^ 1) * PH_B * PH_N + bN;   // best(r-1) picks
    int* cmw = comp + (size_t)par * PH_B * PH_N + bN;
    int* cmr = comp + (size_t)(par ^ 1) * PH_B * PH_N + bN;
    const float* xb = x + (size_t)b * PH_N * 3;

    // ---- stage labels (round 0: identity) ----
    if (r == 0) { for (int i = tid; i < PH_N; i += TPB) scomp[i] = (u16)i; }
    else        { for (int i = tid; i < PH_N; i += TPB) scomp[i] = (u16)cmr[i]; }
    __syncthreads();

    // pre-merge convergence: nothing flushed last round, labels final
    {
        int c0 = scomp[0], diff = 0;
        for (int i = tid; i < PH_N; i += TPB) diff |= (scomp[i] != c0);
        if (!__syncthreads_or(diff)) {
            if (rb == 0) for (int i = tid; i < PH_N; i += TPB) cmw[i] = scomp[i];
            return;
        }
    }

    // ---- merge round r-1 picks (redundant, deterministic roots) ----
    if (r > 0) {
        for (int c = tid; c < PH_N; c += TPB) sbest[c] = cbr[c];   // snapshot
        __syncthreads();
        const u32 mytag = (u32)(ROUNDS - (r - 1));
        // phase 1: parent = target component (self if no valid pick)
        for (int c = tid; c < PH_N; c += TPB) {
            u64 k = sbest[c];
            int pp = c;
            if ((u32)(k >> 54) == mytag) {
                int a = (int)((k >> 11) & 0x7FF), d = (int)(k & 0x7FF);
                int ca = scomp[a], cd = scomp[d];
                pp = (ca == c) ? cd : ca;
            }
            sp[c] = (u16)pp;
        }
        __syncthreads();
        // phase 2a: record deaths once (rb==0 only; mutual pair = same edge)
        if (rb == 0) {
            for (int c = tid; c < PH_N; c += TPB) {
                u64 k = sbest[c];
                if ((u32)(k >> 54) == mytag) {
                    int tc = sp[c];
                    bool mutual = (sp[tc] == c);
                    if (!mutual || c < tc) {
                        int slot = atomicAdd(&cnt[b], 1);
                        dD2[bN + slot] =
                            __uint_as_float((u32)((k >> 22) & 0xFFFFFFFFu));
                    }
                }
            }
        }
        __syncthreads();
        // phase 2b: break 2-cycles (smaller label roots; race-benign)
        for (int c = tid; c < PH_N; c += TPB) {
            u64 k = sbest[c];
            if ((u32)(k >> 54) == mytag) {
                int tc = sp[c];
                if (sp[tc] == c && c < tc) sp[c] = (u16)c;
            }
        }
        __syncthreads();
        // phase 3: in-place pointer jumping. Each sp[c] has one writer per
        // pass; cross-reads of in-flight entries only skip to an ancestor
        // (monotone), final fixed point = unique roots in every block.
        for (int it = 0; it < 12; ++it) {
            int changed = 0;
            for (int c = tid; c < PH_N; c += TPB) {
                u16 t = sp[sp[c]];
                if (t != sp[c]) { sp[c] = t; changed = 1; }
            }
            if (!__syncthreads_or(changed)) break;
        }
        // phase 4: relabel
        for (int v = tid; v < PH_N; v += TPB) scomp[v] = sp[scomp[v]];
        __syncthreads();
    }

    // persist fresh labels; post-merge convergence
    if (rb == 0) for (int i = tid; i < PH_N; i += TPB) cmw[i] = scomp[i];
    {
        int c0 = scomp[0], diff = 0;
        for (int i = tid; i < PH_N; i += TPB) diff |= (scomp[i] != c0);
        if (!__syncthreads_or(diff)) return;
    }
    if (r == ROUNDS) return;   // final merge-only launch

    // ---- best phase: per-row min edge to another component ----
    for (int i = tid; i < PH_N; i += TPB) {
        float px = xb[3 * i], py = xb[3 * i + 1], pz = xb[3 * i + 2];
        spts[i]  = make_float4(px, py, pz, sq3(px, py, pz));
        sbest[i] = ~0ULL;
    }
    __syncthreads();

    float xj[JPL], yj[JPL], zj[JPL], sj[JPL];
    int   cj[JPL];
    #pragma unroll
    for (int k = 0; k < JPL; ++k) {
        float4 qv = spts[lane + (k << 6)];
        xj[k] = qv.x; yj[k] = qv.y; zj[k] = qv.z; sj[k] = qv.w;
        cj[k] = scomp[lane + (k << 6)];
    }

    const float INF = __builtin_inff();
    const u64 tagbits = (u64)(ROUNDS - r) << 54;
    for (int rr = wave; rr < RPB; rr += TPB / 64) {
        const int    i  = rb * RPB + rr;
        const int    ci = scomp[i];
        const float4 pi = spts[i];
        float m[JPL]; int ix[JPL];
        #pragma unroll
        for (int k = 0; k < JPL; ++k) {
            float d2 = d2f(pi.x, pi.y, pi.z, pi.w, xj[k], yj[k], zj[k], sj[k]);
            d2   = fmaxf(d2, 0.0f);                 // = reference max(d2,0)
            m[k] = (cj[k] == ci) ? INF : d2;        // mask same-component
            ix[k] = k;
        }
        #pragma unroll
        for (int s = JPL / 2; s > 0; s >>= 1) {
            #pragma unroll
            for (int k = 0; k < s; ++k)
                if (m[k + s] < m[k]) { m[k] = m[k + s]; ix[k] = ix[k + s]; }
        }
        const float vl = m[0];
        float w = vl;
        w = dpp_min<0x111>(w); w = dpp_min<0x112>(w); w = dpp_min<0x114>(w);
        w = dpp_min<0x118>(w); w = dpp_min<0x142>(w); w = dpp_min<0x143>(w);
        const float wm =
            __int_as_float(__builtin_amdgcn_readlane(__float_as_int(w), 63));
        if (wm < INF) {
            // tie-break consistent with full key: min j among d2-tied lanes
            int jw = lane + (ix[0] << 6);
            int jc = (vl == wm) ? jw : 0x7FFFFFFF;
            jc = dpp_imin<0x111>(jc); jc = dpp_imin<0x112>(jc);
            jc = dpp_imin<0x114>(jc); jc = dpp_imin<0x118>(jc);
            jc = dpp_imin<0x142>(jc); jc = dpp_imin<0x143>(jc);
            const int j = __builtin_amdgcn_readlane(jc, 63);
            if (lane == 0) {
                int a = min(i, j), c2 = max(i, j);
                u64 key = tagbits | ((u64)__float_as_uint(wm) << 22) |
                          ((u64)a << 11) | (u64)c2;
                atomicMin(&sbest[ci], key);
            }
        }
    }
    __syncthreads();
    for (int c = tid; c < PH_N; c += TPB) {
        u64 k = sbest[c];
        if (k != ~0ULL) atomicMin(&cbw[c], k);
    }
}

__global__ __launch_bounds__(1024)
void k_final(const float* __restrict__ deathsD2, const float* __restrict__ filt,
             float* __restrict__ out) {
    __shared__ float deaths[PH_N];
    __shared__ int   scnt[PH_F];
    const int b = blockIdx.x, tid = threadIdx.x, T = 1024;
    const float INF = __builtin_inff();

    for (int t = tid; t < PH_N; t += T) {
        deaths[t] = (t < PH_N - 1)
                        ? sqrtf(deathsD2[(size_t)b * PH_N + t])  // d2 >= 0
                        : -INF;                                  // pad
    }
    __syncthreads();

    // bitonic sort ascending
    for (int k = 2; k <= PH_N; k <<= 1) {
        for (int jj = k >> 1; jj > 0; jj >>= 1) {
            for (int i = tid; i < PH_N; i += T) {
                int ixj = i ^ jj;
                if (ixj > i) {
                    float a = deaths[i];
                    float c = deaths[ixj];
                    bool up = ((i & k) == 0);
                    if (up ? (a > c) : (a < c)) {
                        deaths[i]   = c;
                        deaths[ixj] = a;
                    }
                }
            }
            __syncthreads();
        }
    }

    if (tid < PH_F) {
        float eps = filt[tid];
        int lo = 0, hi = PH_N;
        while (lo < hi) {
            int mid = (lo + hi) >> 1;
            if (deaths[mid] <= eps) lo = mid + 1; else hi = mid;
        }
        scnt[tid] = lo - 1;   // exclude -inf pad
    }
    __syncthreads();

    float* dg = out + (size_t)b * (3 * MAXPTS * 2);
    for (int t = tid; t < 3 * MAXPTS * 2; t += T) {
        float val = 0.0f;
        if (t < 2 * MAXPTS && (t & 1)) {
            int k = t >> 1;
            val = deaths[PH_N - 1 - k];
        }
        dg[t] = val;
    }
    float* bc = out + (size_t)PH_B * (3 * MAXPTS * 2) + (size_t)b * (3 * PH_F);
    for (int t = tid; t < 3 * PH_F; t += T) {
        float val = 0.0f;
        if (t < PH_F) val = (float)(PH_N - scnt[t]);
        bc[t] = val;
    }
}

extern "C" void kernel_launch(void* const* d_in, const int* in_sizes, int n_in,
                              void* d_out, int out_size, void* d_ws, size_t ws_size,
                              hipStream_t stream) {
    const float* x    = (const float*)d_in[0];
    const float* filt = (const float*)d_in[1];
    float* out        = (float*)d_out;

    char* ws = (char*)d_ws;                               // ~900 KB used
    u64*   cbB  = (u64*)ws;                               // [2][B][N] u64
    int*   comp = (int*)(ws + (size_t)2 * PH_B * PH_N * 8);   // [2][B][N] int
    float* dD2  = (float*)(comp + 2 * PH_B * PH_N);       // [B][N]
    int*   cnt  = (int*)(dD2 + PH_B * PH_N);              // [B]

    k_init<<<64, 256, 0, stream>>>(cbB, cnt);
    for (int r = 0; r <= ROUNDS; ++r)
        k_round<<<dim3(RB, PH_B), TPB, 0, stream>>>(x, cbB, comp, dD2, cnt, r);
    k_final<<<PH_B, 1024, 0, stream>>>(dD2, filt, out);
}